// Round 17
// baseline (388.577 us; speedup 1.0000x reference)
//
#include <hip/hip_runtime.h>

#define NB 16
#define TT 8192
#define Bb 4

typedef __attribute__((ext_vector_type(8))) short short8;
typedef __attribute__((ext_vector_type(16))) float f32x16;

__device__ __forceinline__ unsigned short bf16_rn(float f) {
  unsigned int u = __float_as_uint(f);
  u += 0x7FFF + ((u >> 16) & 1);
  return (unsigned short)(u >> 16);
}
__device__ __forceinline__ float bf16_to_f(unsigned short s) {
  return __uint_as_float(((unsigned int)s) << 16);
}
__device__ __forceinline__ unsigned int pack2(float a, float b) {
  return (unsigned int)bf16_rn(a) | ((unsigned int)bf16_rn(b) << 16);
}
// within-16-chunk k -> stored position (same permute on both GEMM operands)
__device__ __forceinline__ int kpos(int k) {
  int g = (k >> 2) & 1;
  int e = (k & 3) + 4 * (k >> 3);
  return g * 8 + e;
}
__device__ __forceinline__ int kinv(int p) {
  int g = p >> 3, e = p & 7;
  return (e & 3) + 4 * g + 8 * (e >> 2);
}

#define WINRD(base, r, off)                                                    \
  (*(const short8*)((char*)(base) +                                            \
      (((unsigned int)((r) * 128 + (off) * 2)) ^                               \
       ((unsigned int)(((r) & 7) << 4)))))

// gather one (cls,tcol) fragment-ordered h chunk: 32 bf16 (A rows then S rows)
// hsrc is h + (b,blk) base + tcol. dst is 64B-aligned, thread-private chunk.
__device__ __forceinline__ void conv_h_chunk(const float* __restrict__ hsrc,
                                             unsigned short* __restrict__ dst,
                                             int cls) {
  const int rb = 4 * (cls & 1) + 32 * (cls >> 1);
#pragma unroll
  for (int jj = 0; jj < 8; ++jj) {   // aA pairs (rows rb + {0,1,2,3,8,..,27})
    int row = ((2 * jj) & 3) + 8 * ((2 * jj) >> 2) + rb;
    ((unsigned int*)dst)[jj] =
        pack2(hsrc[(size_t)row * TT], hsrc[(size_t)(row + 1) * TT]);
  }
#pragma unroll
  for (int jj = 0; jj < 8; ++jj) {   // aS pairs (rows +64)
    int row = 64 + ((2 * jj) & 3) + 8 * ((2 * jj) >> 2) + rb;
    ((unsigned int*)dst)[8 + jj] =
        pack2(hsrc[(size_t)row * TT], hsrc[(size_t)(row + 1) * TT]);
  }
}

// ---------------------------------------------------------------------------
// All weights fp32 -> bf16, k-permuted. One launch. (validated round 4)
__global__ __launch_bounds__(256) void prep_weights(
    const float* __restrict__ wconv, const float* __restrict__ wres,
    const float* __restrict__ wsk, const float* __restrict__ w1,
    const float* __restrict__ w2, short* __restrict__ dwc,
    short* __restrict__ dwr, short* __restrict__ dws,
    short* __restrict__ dw1, short* __restrict__ dw2)
{
  int i = blockIdx.x * 256 + threadIdx.x;
  if (i < 262144) {
    int k = kinv(i & 15);
    int ic = (i & 48) | k;
    int oc = (i >> 6) & 127;
    int tap = (i >> 13) & 1;
    int blk = i >> 14;
    dwc[i] = (short)bf16_rn(wconv[(((blk * 128 + oc) * 64 + ic) << 1) | tap]);
    return;
  }
  int j = i - 262144;
  if (j < 65536) { dwr[j] = (short)bf16_rn(wres[(j & ~15) | kinv(j & 15)]); return; }
  j -= 65536;
  if (j < 262144) { dws[j] = (short)bf16_rn(wsk[(j & ~15) | kinv(j & 15)]); return; }
  j -= 262144;
  if (j < 65536) { dw1[j] = (short)bf16_rn(w1[(j & ~15) | kinv(j & 15)]); return; }
  j -= 65536;
  if (j < 65536) { dw2[j] = (short)bf16_rn(w2[(j & ~15) | kinv(j & 15)]); return; }
}

// ---------------------------------------------------------------------------
// Convert h block 0 to the fragment-permuted bf16 layout h16p:
// [b][blk][cls(4)][tcol(8192)][32]. Blocks 1..15 are converted by the tails
// of block kernels 0..14 (off the serial critical path).
__global__ __launch_bounds__(256) void prep_h0(
    const float* __restrict__ h, unsigned short* __restrict__ h16p)
{
  int idx = blockIdx.x * 256 + threadIdx.x;   // 4b * 4cls * 8192t = 131072
  int tc = idx & 8191;
  int cls = (idx >> 13) & 3;
  int b = idx >> 15;
  const float* hsrc = h + (size_t)b * 2048 * TT + tc;   // blk 0
  unsigned short* dst =
      h16p + (((size_t)(b * NB + 0) * 4 + cls) * TT + tc) * 32;
  conv_h_chunk(hsrc, dst, cls);
}

// ---------------------------------------------------------------------------
// One WaveNet block. Residual carried bf16 k-permuted (R15); h read from the
// fragment-permuted bf16 h16p (4x16B loads/thread). Tail converts h_{blk+1}.
template <int DIL, int FIRST, int LAST>
__global__ __launch_bounds__(256) void block_kernel(
    const unsigned short* __restrict__ rin16, unsigned short* __restrict__ rout16,
    const int* __restrict__ x, const float* __restrict__ embed,
    const float* __restrict__ h, const unsigned short* __restrict__ h16p,
    unsigned short* __restrict__ h16w,   // same buffer, writable (tail)
    const short* __restrict__ wc, const short* __restrict__ wr,
    unsigned short* __restrict__ zg, int blk)
{
  __shared__ short win[2][(32 + DIL) * 64];  // per-tile window (bf16 swizzled)
  __shared__ short zl[2][32 * 64];           // per-tile z

  const int b = blockIdx.y;
  const int tile = threadIdx.x >> 7;          // 0 or 1
  const int htid = threadIdx.x & 127;         // thread id within half
  const int t0 = (blockIdx.x * 2 + tile) * 32;
  const int lane = htid & 63, wv = htid >> 6; // wv in {0,1} within half
  const int l31 = lane & 31, hi = lane >> 5;

  short* winT = win[tile];
  short* zlT = zl[tile];

  // ---- h fragment load: 4 x 16B contiguous (bf16, fragment-permuted) ----
  const int cls = wv * 2 + hi;
  const unsigned short* hp =
      h16p + ((((size_t)(b * NB + blk) * 4 + cls) * TT + (size_t)(t0 + l31)) * 32);
  short8 hq0 = *(const short8*)(hp);
  short8 hq1 = *(const short8*)(hp + 8);
  short8 hq2 = *(const short8*)(hp + 16);
  short8 hq3 = *(const short8*)(hp + 24);
  f32x16 aA, aS;
#pragma unroll
  for (int r = 0; r < 8; ++r) {
    aA[r] = bf16_to_f((unsigned short)hq0[r]);
    aA[r + 8] = bf16_to_f((unsigned short)hq1[r]);
    aS[r] = bf16_to_f((unsigned short)hq2[r]);
    aS[r + 8] = bf16_to_f((unsigned short)hq3[r]);
  }

  // ---- stage window ----
  if (FIRST) {
    const int* xb = x + b * TT;
#pragma unroll
    for (int it = 0; it < 8; ++it) {
      int u = it * 128 + htid;          // 32 rows x 32 pairs
      int cpair = u & 31, t = u >> 5;
      int c0 = cpair * 2;
      int xi = xb[t0 + t];
      float v0 = embed[(size_t)xi * 64 + c0];
      float v1 = embed[(size_t)xi * 64 + c0 + 1];
      int p0 = (c0 & 48) | kpos(c0 & 15);
      int w = DIL + t;                  // DIL == 1
      unsigned int byte = (unsigned int)(w * 128 + p0 * 2) ^
                          (unsigned int)((w & 7) << 4);
      *(unsigned int*)((char*)winT + byte) = pack2(v0, v1);
    }
    if (htid < 32) {                    // halo row t0-1
      int c0 = htid * 2;
      float v0 = 0.f, v1 = 0.f;
      if (t0 > 0) {
        int xi = xb[t0 - 1];
        v0 = embed[(size_t)xi * 64 + c0];
        v1 = embed[(size_t)xi * 64 + c0 + 1];
      }
      int p0 = (c0 & 48) | kpos(c0 & 15);
      unsigned int byte = (unsigned int)(p0 * 2);   // w = 0
      *(unsigned int*)((char*)winT + byte) = pack2(v0, v1);
    }
  } else {
    const unsigned short* rb16 = rin16 + (size_t)b * TT * 64;
#pragma unroll
    for (int it = 0; it < 2; ++it) {
      int u = it * 128 + htid;          // 32 rows x 8 groups(8ch)
      int q = u & 7, t = u >> 3;
      short8 v = *(const short8*)(rb16 + (size_t)(t0 + t) * 64 + q * 8);
      int w = DIL + t;
      unsigned int byte = (unsigned int)(w * 128 + q * 16) ^
                          (unsigned int)((w & 7) << 4);
      *(short8*)((char*)winT + byte) = v;
    }
    for (int u = htid; u < DIL * 8; u += 128) {   // halo rows [t0-DIL, t0)
      int q = u & 7, w = u >> 3;
      int gt = t0 - DIL + w;
      short8 v = {};
      if (gt >= 0) v = *(const short8*)(rb16 + (size_t)gt * 64 + q * 8);
      unsigned int byte = (unsigned int)(w * 128 + q * 16) ^
                          (unsigned int)((w & 7) << 4);
      *(short8*)((char*)winT + byte) = v;
    }
  }
  __syncthreads();

  // ---- conv: two K=64 tap GEMMs (acc pre-init from h). D[row=oc][col=t] ----
  const short* wA0 = wc + (size_t)blk * 16384 + (32 * wv + l31) * 64;  // tap0
  const short* wA1 = wA0 + 8192;                                       // tap1
  const int r1 = DIL + l31;   // x[t]
  const int r0 = l31;         // x[t-DIL]
#pragma unroll
  for (int ks = 0; ks < 4; ++ks) {
    int off = ks * 16 + 8 * hi;
    short8 b1 = WINRD(winT, r1, off);
    short8 b0 = WINRD(winT, r0, off);
    short8 a0t = *(const short8*)(wA0 + off);
    short8 a1t = *(const short8*)(wA1 + off);
    short8 a0s = *(const short8*)(wA0 + 4096 + off);
    short8 a1s = *(const short8*)(wA1 + 4096 + off);
    aA = __builtin_amdgcn_mfma_f32_32x32x16_bf16(a0t, b0, aA, 0, 0, 0);
    aA = __builtin_amdgcn_mfma_f32_32x32x16_bf16(a1t, b1, aA, 0, 0, 0);
    aS = __builtin_amdgcn_mfma_f32_32x32x16_bf16(a0s, b0, aS, 0, 0, 0);
    aS = __builtin_amdgcn_mfma_f32_32x32x16_bf16(a1s, b1, aS, 0, 0, 0);
  }

  // ---- gated activation -> zl ----
#pragma unroll
  for (int r = 0; r < 16; r += 2) {
    int ic0 = (r & 3) + 4 * hi + 8 * (r >> 2) + 32 * wv;  // even
    float z0 = (1.f - 2.f / (__expf(2.f * aA[r]) + 1.f)) *
               (1.f / (1.f + __expf(-aS[r])));
    float z1 = (1.f - 2.f / (__expf(2.f * aA[r + 1]) + 1.f)) *
               (1.f / (1.f + __expf(-aS[r + 1])));
    int p = (ic0 & ~15) | kpos(ic0 & 15);
    int tloc = l31;                                       // D col = t
    unsigned int byte = (unsigned int)(tloc * 128 + p * 2) ^
                        (unsigned int)((tloc & 7) << 4);
    *(unsigned int*)((char*)zlT + byte) = pack2(z0, z1);
  }
  __syncthreads();

  // ---- z -> zg (coalesced u32 from LDS; head does the K=1024 skip GEMM) ----
  {
    unsigned short* zb = zg + ((size_t)(blk * Bb + b) * TT + t0) * 64;
#pragma unroll
    for (int it = 0; it < 8; ++it) {
      int u = it * 128 + htid;          // 32 rows x 32 u32
      int p2 = u & 31, t = u >> 5;
      unsigned int byte = (unsigned int)(t * 128 + p2 * 4) ^
                          (unsigned int)((t & 7) << 4);
      unsigned int v = *(const unsigned int*)((char*)zlT + byte);
      *(unsigned int*)(zb + (size_t)t * 64 + p2 * 2) = v;
    }
  }

  // ---- residual: rout16 = bf16(rin16 + z @ wres^T). D[row=t][col=oc] ----
  if (!LAST) {
    const int trow = l31;
    f32x16 ar = {};
    const short* wrb = wr + (size_t)blk * 4096 + (wv * 32 + l31) * 64;
#pragma unroll
    for (int ks = 0; ks < 4; ++ks) {
      int off = ks * 16 + 8 * hi;
      short8 az = WINRD(zlT, trow, off);
      short8 bw = *(const short8*)(wrb + off);
      ar = __builtin_amdgcn_mfma_f32_32x32x16_bf16(az, bw, ar, 0, 0, 0);
    }
    unsigned short* obase = rout16 + (size_t)b * TT * 64;
    int oc = wv * 32 + l31;
    int ocp = (oc & 48) | kpos(oc & 15);
#pragma unroll
    for (int r = 0; r < 16; ++r) {
      int t = (r & 3) + 4 * hi + 8 * (r >> 2);           // 0..31
      int w = DIL + t;
      unsigned short ov = *(const unsigned short*)((char*)winT +
          (((unsigned int)(w * 128 + ocp * 2)) ^ ((unsigned int)((w & 7) << 4))));
      obase[(size_t)(t0 + t) * 64 + ocp] = bf16_rn(bf16_to_f(ov) + ar[r]);
    }
  }

  // ---- tail: convert h_{blk+1} to h16p (off the serial critical path) ----
  if (!LAST) {
    const int tb = blockIdx.x * 64;          // this WG's 64 tcols
    const int tcl = threadIdx.x & 63;
    const int tcls = threadIdx.x >> 6;       // 0..3
    const int tc = tb + tcl;
    const float* hsrc = h + ((size_t)b * 2048 + (size_t)(blk + 1) * 128) * TT + tc;
    unsigned short* dst =
        h16w + (((size_t)(b * NB + blk + 1) * 4 + tcls) * TT + tc) * 32;
    conv_h_chunk(hsrc, dst, tcls);
  }
}

// ---------------------------------------------------------------------------
// head (validated round 8): skip = sum_blk wsk_blk @ z_blk; relu; w1; relu; w2.
__global__ __launch_bounds__(256) void head_kernel(
    const unsigned short* __restrict__ zg, const short* __restrict__ wsk,
    const short* __restrict__ w1, const short* __restrict__ w2,
    float* __restrict__ out)
{
  __shared__ short zbuf[2][32 * 64];
  __shared__ short yb[32 * 256];
  __shared__ short y2b[32 * 256];

  const int b = blockIdx.y;
  const int t0 = blockIdx.x * 32;
  const int tid = threadIdx.x;
  const int lane = tid & 63, wv = tid >> 6;
  const int l31 = lane & 31, hi = lane >> 5;

  {
#pragma unroll
    for (int it = 0; it < 4; ++it) {
      int u = it * 256 + tid;
      int p2 = u & 31, t = u >> 5;
      unsigned int v = *(const unsigned int*)(zg +
          ((size_t)(0 * Bb + b) * TT + t0 + t) * 64 + p2 * 2);
      unsigned int byte = (unsigned int)(t * 128 + p2 * 4) ^
                          (unsigned int)((t & 7) << 4);
      *(unsigned int*)((char*)zbuf[0] + byte) = v;
    }
  }

  f32x16 acc0 = {}, acc1 = {};
  const short* wsb0 = wsk + (wv * 32 + l31) * 64;
  const short* wsb1 = wsk + ((wv + 4) * 32 + l31) * 64;

  for (int blk = 0; blk < NB; ++blk) {
    __syncthreads();
    if (blk < NB - 1) {
#pragma unroll
      for (int it = 0; it < 4; ++it) {
        int u = it * 256 + tid;
        int p2 = u & 31, t = u >> 5;
        unsigned int v = *(const unsigned int*)(zg +
            ((size_t)((blk + 1) * Bb + b) * TT + t0 + t) * 64 + p2 * 2);
        unsigned int byte = (unsigned int)(t * 128 + p2 * 4) ^
                            (unsigned int)((t & 7) << 4);
        *(unsigned int*)((char*)zbuf[(blk + 1) & 1] + byte) = v;
      }
    }
    const short* zb = zbuf[blk & 1];
#pragma unroll
    for (int ks = 0; ks < 4; ++ks) {
      int off = ks * 16 + 8 * hi;
      short8 bw0 = *(const short8*)(wsb0 + (size_t)blk * 16384 + off);
      short8 bw1 = *(const short8*)(wsb1 + (size_t)blk * 16384 + off);
      short8 az = WINRD(zb, l31, off);
      acc0 = __builtin_amdgcn_mfma_f32_32x32x16_bf16(az, bw0, acc0, 0, 0, 0);
      acc1 = __builtin_amdgcn_mfma_f32_32x32x16_bf16(az, bw1, acc1, 0, 0, 0);
    }
  }

  {
    int sk0 = wv * 32 + l31;
    int sk1 = sk0 + 128;
    int p0 = (sk0 & 0xF0) | kpos(sk0 & 15);
    int p1 = (sk1 & 0xF0) | kpos(sk1 & 15);
#pragma unroll
    for (int r = 0; r < 16; ++r) {
      int dt = (r & 3) + 4 * hi + 8 * (r >> 2);
      unsigned int b0 = (unsigned int)(dt * 512 + p0 * 2) ^
                        (unsigned int)((dt & 7) << 4);
      unsigned int b1 = (unsigned int)(dt * 512 + p1 * 2) ^
                        (unsigned int)((dt & 7) << 4);
      *(short*)((char*)yb + b0) = (short)bf16_rn(fmaxf(acc0[r], 0.f));
      *(short*)((char*)yb + b1) = (short)bf16_rn(fmaxf(acc1[r], 0.f));
    }
  }
  __syncthreads();

#pragma unroll
  for (int ot = 0; ot < 2; ++ot) {
    const short* w1r = w1 + ((wv + 4 * ot) * 32 + l31) * 256;
    const int trow = l31;
    f32x16 acc = {};
#pragma unroll
    for (int ks = 0; ks < 16; ++ks) {
      int off = ks * 16 + 8 * hi;
      short8 by = *(const short8*)((char*)yb +
          ((unsigned int)(trow * 512 + off * 2) ^ (unsigned int)((trow & 7) << 4)));
      short8 aw = *(const short8*)(w1r + off);
      acc = __builtin_amdgcn_mfma_f32_32x32x16_bf16(aw, by, acc, 0, 0, 0);
    }
#pragma unroll
    for (int r = 0; r < 16; r += 2) {
      int o0 = (wv + 4 * ot) * 32 + (r & 3) + 4 * hi + 8 * (r >> 2);
      unsigned int v = (unsigned int)bf16_rn(fmaxf(acc[r], 0.f)) |
                       ((unsigned int)bf16_rn(fmaxf(acc[r + 1], 0.f)) << 16);
      int p = (o0 & 0xF0) | kpos(o0 & 15);
      unsigned int byte = (unsigned int)(trow * 512 + p * 2) ^
                          (unsigned int)((trow & 7) << 4);
      *(unsigned int*)((char*)y2b + byte) = v;
    }
  }
  __syncthreads();

  {
    float* ob = out + (size_t)b * 256 * TT;
#pragma unroll
    for (int ot = 0; ot < 2; ++ot) {
      const short* w2r = w2 + ((wv + 4 * ot) * 32 + l31) * 256;
      const int trow = l31;
      f32x16 acc = {};
#pragma unroll
      for (int ks = 0; ks < 16; ++ks) {
        int off = ks * 16 + 8 * hi;
        short8 by = *(const short8*)((char*)y2b +
            ((unsigned int)(trow * 512 + off * 2) ^ (unsigned int)((trow & 7) << 4)));
        short8 aw = *(const short8*)(w2r + off);
        acc = __builtin_amdgcn_mfma_f32_32x32x16_bf16(aw, by, acc, 0, 0, 0);
      }
#pragma unroll
      for (int r = 0; r < 16; ++r) {
        int oc = (wv + 4 * ot) * 32 + (r & 3) + 4 * hi + 8 * (r >> 2);
        ob[(size_t)oc * TT + t0 + trow] = acc[r];
      }
    }
  }
}

// ---------------------------------------------------------------------------
extern "C" void kernel_launch(void* const* d_in, const int* in_sizes, int n_in,
                              void* d_out, int out_size, void* d_ws, size_t ws_size,
                              hipStream_t stream)
{
  const int* x = (const int*)d_in[0];
  const float* h = (const float*)d_in[1];
  const float* embed = (const float*)d_in[2];
  const float* w_conv = (const float*)d_in[3];
  const float* w_res = (const float*)d_in[4];
  const float* w_skip = (const float*)d_in[5];
  const float* w_out1 = (const float*)d_in[6];
  const float* w_out2 = (const float*)d_in[7];
  float* out = (float*)d_out;

  char* ws = (char*)d_ws;
  unsigned short* r0 = (unsigned short*)ws;                         // 4 MB
  unsigned short* r1 = (unsigned short*)(ws + (size_t)(4 << 20));   // 4 MB
  unsigned short* zg = (unsigned short*)(ws + (size_t)(8 << 20));   // 64 MB
  unsigned short* h16p = (unsigned short*)(ws + (size_t)(72 << 20)); // 128 MB
  short* dwc = (short*)(ws + (size_t)(200 << 20));                  // 512 KB
  short* dwr = dwc + 262144;
  short* dws = dwr + 65536;
  short* dw1 = dws + 262144;
  short* dw2 = dw1 + 65536;

  prep_weights<<<2816, 256, 0, stream>>>(w_conv, w_res, w_skip, w_out1, w_out2,
                                         dwc, dwr, dws, dw1, dw2);
  prep_h0<<<512, 256, 0, stream>>>(h, h16p);

  unsigned short* rf[2] = {r0, r1};
  const dim3 grid(TT / 64, Bb);

#define LAUNCH_BLK(DIL, FIRST, LAST, i)                                        \
  block_kernel<DIL, FIRST, LAST><<<grid, 256, 0, stream>>>(                    \
      rf[(i) & 1], rf[((i) + 1) & 1], x, embed, h, h16p, h16p, dwc, dwr, zg, (i))

  LAUNCH_BLK(1, 1, 0, 0);
  LAUNCH_BLK(2, 0, 0, 1);
  LAUNCH_BLK(4, 0, 0, 2);
  LAUNCH_BLK(8, 0, 0, 3);
  LAUNCH_BLK(16, 0, 0, 4);
  LAUNCH_BLK(32, 0, 0, 5);
  LAUNCH_BLK(64, 0, 0, 6);
  LAUNCH_BLK(128, 0, 0, 7);
  LAUNCH_BLK(1, 0, 0, 8);
  LAUNCH_BLK(2, 0, 0, 9);
  LAUNCH_BLK(4, 0, 0, 10);
  LAUNCH_BLK(8, 0, 0, 11);
  LAUNCH_BLK(16, 0, 0, 12);
  LAUNCH_BLK(32, 0, 0, 13);
  LAUNCH_BLK(64, 0, 0, 14);
  LAUNCH_BLK(128, 0, 1, 15);
#undef LAUNCH_BLK

  head_kernel<<<dim3(TT / 32, Bb), 256, 0, stream>>>(zg, dws, dw1, dw2, out);
}

// Round 18
// 323.628 us; speedup vs baseline: 1.2007x; 1.2007x over previous
//
#include <hip/hip_runtime.h>

#define NB 16
#define TT 8192
#define Bb 4

typedef __attribute__((ext_vector_type(8))) short short8;
typedef __attribute__((ext_vector_type(16))) float f32x16;

__device__ __forceinline__ unsigned short bf16_rn(float f) {
  unsigned int u = __float_as_uint(f);
  u += 0x7FFF + ((u >> 16) & 1);
  return (unsigned short)(u >> 16);
}
__device__ __forceinline__ float bf16_to_f(unsigned short s) {
  return __uint_as_float(((unsigned int)s) << 16);
}
__device__ __forceinline__ unsigned int pack2(float a, float b) {
  return (unsigned int)bf16_rn(a) | ((unsigned int)bf16_rn(b) << 16);
}
// within-16-chunk k -> stored position (same permute on both GEMM operands)
__device__ __forceinline__ int kpos(int k) {
  int g = (k >> 2) & 1;
  int e = (k & 3) + 4 * (k >> 3);
  return g * 8 + e;
}
__device__ __forceinline__ int kinv(int p) {
  int g = p >> 3, e = p & 7;
  return (e & 3) + 4 * g + 8 * (e >> 2);
}

#define WINRD(base, r, off)                                                    \
  (*(const short8*)((char*)(base) +                                            \
      (((unsigned int)((r) * 128 + (off) * 2)) ^                               \
       ((unsigned int)(((r) & 7) << 4)))))

// ---------------------------------------------------------------------------
// All weights fp32 -> bf16, k-permuted. One launch. (validated round 4)
__global__ __launch_bounds__(256) void prep_weights(
    const float* __restrict__ wconv, const float* __restrict__ wres,
    const float* __restrict__ wsk, const float* __restrict__ w1,
    const float* __restrict__ w2, short* __restrict__ dwc,
    short* __restrict__ dwr, short* __restrict__ dws,
    short* __restrict__ dw1, short* __restrict__ dw2)
{
  int i = blockIdx.x * 256 + threadIdx.x;
  if (i < 262144) {
    int k = kinv(i & 15);
    int ic = (i & 48) | k;
    int oc = (i >> 6) & 127;
    int tap = (i >> 13) & 1;
    int blk = i >> 14;
    dwc[i] = (short)bf16_rn(wconv[(((blk * 128 + oc) * 64 + ic) << 1) | tap]);
    return;
  }
  int j = i - 262144;
  if (j < 65536) { dwr[j] = (short)bf16_rn(wres[(j & ~15) | kinv(j & 15)]); return; }
  j -= 65536;
  if (j < 262144) { dws[j] = (short)bf16_rn(wsk[(j & ~15) | kinv(j & 15)]); return; }
  j -= 262144;
  if (j < 65536) { dw1[j] = (short)bf16_rn(w1[(j & ~15) | kinv(j & 15)]); return; }
  j -= 65536;
  if (j < 65536) { dw2[j] = (short)bf16_rn(w2[(j & ~15) | kinv(j & 15)]); return; }
}

// ---------------------------------------------------------------------------
// One WaveNet block. Residual stream carried as bf16 k-permuted [b][t][cp]
// (halves the serial chain's resid bytes; staging is raw short8 copies).
// TWO independent 32-row tiles per WG (256 thr). blk==0 gathers embed.
template <int DIL, int FIRST, int LAST>
__global__ __launch_bounds__(256) void block_kernel(
    const unsigned short* __restrict__ rin16, unsigned short* __restrict__ rout16,
    const int* __restrict__ x, const float* __restrict__ embed,
    const float* __restrict__ h, const short* __restrict__ wc,
    const short* __restrict__ wr, unsigned short* __restrict__ zg,
    int blk)
{
  __shared__ short win[2][(32 + DIL) * 64];  // per-tile window (bf16 swizzled)
  __shared__ short zl[2][32 * 64];           // per-tile z

  const int b = blockIdx.y;
  const int tile = threadIdx.x >> 7;          // 0 or 1
  const int htid = threadIdx.x & 127;         // thread id within half
  const int t0 = (blockIdx.x * 2 + tile) * 32;
  const int lane = htid & 63, wv = htid >> 6; // wv in {0,1} within half
  const int l31 = lane & 31, hi = lane >> 5;

  short* winT = win[tile];
  short* zlT = zl[tile];

  // ---- h loads issued first (latency hides under staging; fp32 exact) ----
  const int tcol = t0 + l31;
  f32x16 aA, aS;
  const float* hb = h + ((size_t)b * 2048 + (size_t)blk * 128) * TT;
#pragma unroll
  for (int r = 0; r < 16; ++r) {
    int row = (r & 3) + 4 * hi + 8 * (r >> 2) + 32 * wv;  // 0..63
    aA[r] = hb[(size_t)row * TT + tcol];
    aS[r] = hb[(size_t)(row + 64) * TT + tcol];
  }

  // ---- stage window ----
  if (FIRST) {
    const int* xb = x + b * TT;
#pragma unroll
    for (int it = 0; it < 8; ++it) {
      int u = it * 128 + htid;          // 32 rows x 32 pairs
      int cpair = u & 31, t = u >> 5;
      int c0 = cpair * 2;
      int xi = xb[t0 + t];
      float v0 = embed[(size_t)xi * 64 + c0];
      float v1 = embed[(size_t)xi * 64 + c0 + 1];
      int p0 = (c0 & 48) | kpos(c0 & 15);
      int w = DIL + t;                  // DIL == 1
      unsigned int byte = (unsigned int)(w * 128 + p0 * 2) ^
                          (unsigned int)((w & 7) << 4);
      *(unsigned int*)((char*)winT + byte) = pack2(v0, v1);
    }
    if (htid < 32) {                    // halo row t0-1
      int c0 = htid * 2;
      float v0 = 0.f, v1 = 0.f;
      if (t0 > 0) {
        int xi = xb[t0 - 1];
        v0 = embed[(size_t)xi * 64 + c0];
        v1 = embed[(size_t)xi * 64 + c0 + 1];
      }
      int p0 = (c0 & 48) | kpos(c0 & 15);
      unsigned int byte = (unsigned int)(p0 * 2);   // w = 0
      *(unsigned int*)((char*)winT + byte) = pack2(v0, v1);
    }
  } else {
    const unsigned short* rb16 = rin16 + (size_t)b * TT * 64;
#pragma unroll
    for (int it = 0; it < 2; ++it) {
      int u = it * 128 + htid;          // 32 rows x 8 groups(8ch)
      int q = u & 7, t = u >> 3;
      short8 v = *(const short8*)(rb16 + (size_t)(t0 + t) * 64 + q * 8);
      int w = DIL + t;
      unsigned int byte = (unsigned int)(w * 128 + q * 16) ^
                          (unsigned int)((w & 7) << 4);
      *(short8*)((char*)winT + byte) = v;
    }
    for (int u = htid; u < DIL * 8; u += 128) {   // halo rows [t0-DIL, t0)
      int q = u & 7, w = u >> 3;
      int gt = t0 - DIL + w;
      short8 v = {};
      if (gt >= 0) v = *(const short8*)(rb16 + (size_t)gt * 64 + q * 8);
      unsigned int byte = (unsigned int)(w * 128 + q * 16) ^
                          (unsigned int)((w & 7) << 4);
      *(short8*)((char*)winT + byte) = v;
    }
  }
  __syncthreads();

  // ---- conv: two K=64 tap GEMMs (acc pre-init from h). D[row=oc][col=t] ----
  const short* wA0 = wc + (size_t)blk * 16384 + (32 * wv + l31) * 64;  // tap0
  const short* wA1 = wA0 + 8192;                                       // tap1
  const int r1 = DIL + l31;   // x[t]
  const int r0 = l31;         // x[t-DIL]
#pragma unroll
  for (int ks = 0; ks < 4; ++ks) {
    int off = ks * 16 + 8 * hi;
    short8 b1 = WINRD(winT, r1, off);
    short8 b0 = WINRD(winT, r0, off);
    short8 a0t = *(const short8*)(wA0 + off);
    short8 a1t = *(const short8*)(wA1 + off);
    short8 a0s = *(const short8*)(wA0 + 4096 + off);
    short8 a1s = *(const short8*)(wA1 + 4096 + off);
    aA = __builtin_amdgcn_mfma_f32_32x32x16_bf16(a0t, b0, aA, 0, 0, 0);
    aA = __builtin_amdgcn_mfma_f32_32x32x16_bf16(a1t, b1, aA, 0, 0, 0);
    aS = __builtin_amdgcn_mfma_f32_32x32x16_bf16(a0s, b0, aS, 0, 0, 0);
    aS = __builtin_amdgcn_mfma_f32_32x32x16_bf16(a1s, b1, aS, 0, 0, 0);
  }

  // ---- gated activation -> zl ----
#pragma unroll
  for (int r = 0; r < 16; r += 2) {
    int ic0 = (r & 3) + 4 * hi + 8 * (r >> 2) + 32 * wv;  // even
    float z0 = (1.f - 2.f / (__expf(2.f * aA[r]) + 1.f)) *
               (1.f / (1.f + __expf(-aS[r])));
    float z1 = (1.f - 2.f / (__expf(2.f * aA[r + 1]) + 1.f)) *
               (1.f / (1.f + __expf(-aS[r + 1])));
    int p = (ic0 & ~15) | kpos(ic0 & 15);
    int tloc = l31;                                       // D col = t
    unsigned int byte = (unsigned int)(tloc * 128 + p * 2) ^
                        (unsigned int)((tloc & 7) << 4);
    *(unsigned int*)((char*)zlT + byte) = pack2(z0, z1);
  }
  __syncthreads();

  // ---- z -> zg (coalesced u32 from LDS; head does the K=1024 skip GEMM) ----
  {
    unsigned short* zb = zg + ((size_t)(blk * Bb + b) * TT + t0) * 64;
#pragma unroll
    for (int it = 0; it < 8; ++it) {
      int u = it * 128 + htid;          // 32 rows x 32 u32
      int p2 = u & 31, t = u >> 5;
      unsigned int byte = (unsigned int)(t * 128 + p2 * 4) ^
                          (unsigned int)((t & 7) << 4);
      unsigned int v = *(const unsigned int*)((char*)zlT + byte);
      *(unsigned int*)(zb + (size_t)t * 64 + p2 * 2) = v;
    }
  }

  // ---- residual: rout16 = bf16(rin16 + z @ wres^T). D[row=t][col=oc] ----
  if (!LAST) {
    const int trow = l31;
    f32x16 ar = {};
    const short* wrb = wr + (size_t)blk * 4096 + (wv * 32 + l31) * 64;
#pragma unroll
    for (int ks = 0; ks < 4; ++ks) {
      int off = ks * 16 + 8 * hi;
      short8 az = WINRD(zlT, trow, off);
      short8 bw = *(const short8*)(wrb + off);
      ar = __builtin_amdgcn_mfma_f32_32x32x16_bf16(az, bw, ar, 0, 0, 0);
    }
    unsigned short* obase = rout16 + (size_t)b * TT * 64;
    int oc = wv * 32 + l31;
    int ocp = (oc & 48) | kpos(oc & 15);
#pragma unroll
    for (int r = 0; r < 16; ++r) {
      int t = (r & 3) + 4 * hi + 8 * (r >> 2);           // 0..31
      int w = DIL + t;
      unsigned short ov = *(const unsigned short*)((char*)winT +
          (((unsigned int)(w * 128 + ocp * 2)) ^ ((unsigned int)((w & 7) << 4))));
      obase[(size_t)(t0 + t) * 64 + ocp] = bf16_rn(bf16_to_f(ov) + ar[r]);
    }
  }
}

// ---------------------------------------------------------------------------
// head (validated round 8): skip = sum_blk wsk_blk @ z_blk; relu; w1; relu; w2.
__global__ __launch_bounds__(256) void head_kernel(
    const unsigned short* __restrict__ zg, const short* __restrict__ wsk,
    const short* __restrict__ w1, const short* __restrict__ w2,
    float* __restrict__ out)
{
  __shared__ short zbuf[2][32 * 64];
  __shared__ short yb[32 * 256];
  __shared__ short y2b[32 * 256];

  const int b = blockIdx.y;
  const int t0 = blockIdx.x * 32;
  const int tid = threadIdx.x;
  const int lane = tid & 63, wv = tid >> 6;
  const int l31 = lane & 31, hi = lane >> 5;

  {
#pragma unroll
    for (int it = 0; it < 4; ++it) {
      int u = it * 256 + tid;
      int p2 = u & 31, t = u >> 5;
      unsigned int v = *(const unsigned int*)(zg +
          ((size_t)(0 * Bb + b) * TT + t0 + t) * 64 + p2 * 2);
      unsigned int byte = (unsigned int)(t * 128 + p2 * 4) ^
                          (unsigned int)((t & 7) << 4);
      *(unsigned int*)((char*)zbuf[0] + byte) = v;
    }
  }

  f32x16 acc0 = {}, acc1 = {};
  const short* wsb0 = wsk + (wv * 32 + l31) * 64;
  const short* wsb1 = wsk + ((wv + 4) * 32 + l31) * 64;

  for (int blk = 0; blk < NB; ++blk) {
    __syncthreads();
    if (blk < NB - 1) {
#pragma unroll
      for (int it = 0; it < 4; ++it) {
        int u = it * 256 + tid;
        int p2 = u & 31, t = u >> 5;
        unsigned int v = *(const unsigned int*)(zg +
            ((size_t)((blk + 1) * Bb + b) * TT + t0 + t) * 64 + p2 * 2);
        unsigned int byte = (unsigned int)(t * 128 + p2 * 4) ^
                            (unsigned int)((t & 7) << 4);
        *(unsigned int*)((char*)zbuf[(blk + 1) & 1] + byte) = v;
      }
    }
    const short* zb = zbuf[blk & 1];
#pragma unroll
    for (int ks = 0; ks < 4; ++ks) {
      int off = ks * 16 + 8 * hi;
      short8 bw0 = *(const short8*)(wsb0 + (size_t)blk * 16384 + off);
      short8 bw1 = *(const short8*)(wsb1 + (size_t)blk * 16384 + off);
      short8 az = WINRD(zb, l31, off);
      acc0 = __builtin_amdgcn_mfma_f32_32x32x16_bf16(az, bw0, acc0, 0, 0, 0);
      acc1 = __builtin_amdgcn_mfma_f32_32x32x16_bf16(az, bw1, acc1, 0, 0, 0);
    }
  }

  {
    int sk0 = wv * 32 + l31;
    int sk1 = sk0 + 128;
    int p0 = (sk0 & 0xF0) | kpos(sk0 & 15);
    int p1 = (sk1 & 0xF0) | kpos(sk1 & 15);
#pragma unroll
    for (int r = 0; r < 16; ++r) {
      int dt = (r & 3) + 4 * hi + 8 * (r >> 2);
      unsigned int b0 = (unsigned int)(dt * 512 + p0 * 2) ^
                        (unsigned int)((dt & 7) << 4);
      unsigned int b1 = (unsigned int)(dt * 512 + p1 * 2) ^
                        (unsigned int)((dt & 7) << 4);
      *(short*)((char*)yb + b0) = (short)bf16_rn(fmaxf(acc0[r], 0.f));
      *(short*)((char*)yb + b1) = (short)bf16_rn(fmaxf(acc1[r], 0.f));
    }
  }
  __syncthreads();

#pragma unroll
  for (int ot = 0; ot < 2; ++ot) {
    const short* w1r = w1 + ((wv + 4 * ot) * 32 + l31) * 256;
    const int trow = l31;
    f32x16 acc = {};
#pragma unroll
    for (int ks = 0; ks < 16; ++ks) {
      int off = ks * 16 + 8 * hi;
      short8 by = *(const short8*)((char*)yb +
          ((unsigned int)(trow * 512 + off * 2) ^ (unsigned int)((trow & 7) << 4)));
      short8 aw = *(const short8*)(w1r + off);
      acc = __builtin_amdgcn_mfma_f32_32x32x16_bf16(aw, by, acc, 0, 0, 0);
    }
#pragma unroll
    for (int r = 0; r < 16; r += 2) {
      int o0 = (wv + 4 * ot) * 32 + (r & 3) + 4 * hi + 8 * (r >> 2);
      unsigned int v = (unsigned int)bf16_rn(fmaxf(acc[r], 0.f)) |
                       ((unsigned int)bf16_rn(fmaxf(acc[r + 1], 0.f)) << 16);
      int p = (o0 & 0xF0) | kpos(o0 & 15);
      unsigned int byte = (unsigned int)(trow * 512 + p * 2) ^
                          (unsigned int)((trow & 7) << 4);
      *(unsigned int*)((char*)y2b + byte) = v;
    }
  }
  __syncthreads();

  {
    float* ob = out + (size_t)b * 256 * TT;
#pragma unroll
    for (int ot = 0; ot < 2; ++ot) {
      const short* w2r = w2 + ((wv + 4 * ot) * 32 + l31) * 256;
      const int trow = l31;
      f32x16 acc = {};
#pragma unroll
      for (int ks = 0; ks < 16; ++ks) {
        int off = ks * 16 + 8 * hi;
        short8 by = *(const short8*)((char*)y2b +
            ((unsigned int)(trow * 512 + off * 2) ^ (unsigned int)((trow & 7) << 4)));
        short8 aw = *(const short8*)(w2r + off);
        acc = __builtin_amdgcn_mfma_f32_32x32x16_bf16(aw, by, acc, 0, 0, 0);
      }
#pragma unroll
      for (int r = 0; r < 16; ++r) {
        int oc = (wv + 4 * ot) * 32 + (r & 3) + 4 * hi + 8 * (r >> 2);
        ob[(size_t)oc * TT + t0 + trow] = acc[r];
      }
    }
  }
}

// ---------------------------------------------------------------------------
extern "C" void kernel_launch(void* const* d_in, const int* in_sizes, int n_in,
                              void* d_out, int out_size, void* d_ws, size_t ws_size,
                              hipStream_t stream)
{
  const int* x = (const int*)d_in[0];
  const float* h = (const float*)d_in[1];
  const float* embed = (const float*)d_in[2];
  const float* w_conv = (const float*)d_in[3];
  const float* w_res = (const float*)d_in[4];
  const float* w_skip = (const float*)d_in[5];
  const float* w_out1 = (const float*)d_in[6];
  const float* w_out2 = (const float*)d_in[7];
  float* out = (float*)d_out;

  char* ws = (char*)d_ws;
  unsigned short* r0 = (unsigned short*)ws;                      // 4 MB
  unsigned short* r1 = (unsigned short*)(ws + (size_t)(4 << 20)); // 4 MB
  unsigned short* zg = (unsigned short*)(ws + (size_t)(8 << 20)); // 64 MB
  short* dwc = (short*)(ws + (size_t)(72 << 20));                // 512 KB
  short* dwr = dwc + 262144;
  short* dws = dwr + 65536;
  short* dw1 = dws + 262144;
  short* dw2 = dw1 + 65536;

  prep_weights<<<2816, 256, 0, stream>>>(w_conv, w_res, w_skip, w_out1, w_out2,
                                         dwc, dwr, dws, dw1, dw2);

  unsigned short* rf[2] = {r0, r1};
  const dim3 grid(TT / 64, Bb);

#define LAUNCH_BLK(DIL, FIRST, LAST, i)                                        \
  block_kernel<DIL, FIRST, LAST><<<grid, 256, 0, stream>>>(                    \
      rf[(i) & 1], rf[((i) + 1) & 1], x, embed, h, dwc, dwr, zg, (i))

  LAUNCH_BLK(1, 1, 0, 0);
  LAUNCH_BLK(2, 0, 0, 1);
  LAUNCH_BLK(4, 0, 0, 2);
  LAUNCH_BLK(8, 0, 0, 3);
  LAUNCH_BLK(16, 0, 0, 4);
  LAUNCH_BLK(32, 0, 0, 5);
  LAUNCH_BLK(64, 0, 0, 6);
  LAUNCH_BLK(128, 0, 0, 7);
  LAUNCH_BLK(1, 0, 0, 8);
  LAUNCH_BLK(2, 0, 0, 9);
  LAUNCH_BLK(4, 0, 0, 10);
  LAUNCH_BLK(8, 0, 0, 11);
  LAUNCH_BLK(16, 0, 0, 12);
  LAUNCH_BLK(32, 0, 0, 13);
  LAUNCH_BLK(64, 0, 0, 14);
  LAUNCH_BLK(128, 0, 1, 15);
#undef LAUNCH_BLK

  head_kernel<<<dim3(TT / 32, Bb), 256, 0, stream>>>(zg, dws, dw1, dw2, out);
}